// Round 12
// baseline (695.404 us; speedup 1.0000x reference)
//
#include <hip/hip_runtime.h>

// TPF encoder, MFMA fp16, CSR aggregation. r12 = r11 + template-correct raw
// barriers in edge_async.
//
// r11 (659us, best): edge_async L2 (LDS weights, reg prefetch, __syncthreads)
// + r8 everything else. Remaining flaw: __syncthreads' structural
// s_waitcnt vmcnt(0) drains the cross-tile prefetch at the FIRST LN barrier,
// so the random-gather latency gets only ~200cy of cover. r10's raw-barrier
// attempt regressed because it added sched_barrier(0) + a combined asm barrier
// (m141 schedule-pinning). This round uses the guide's verified T3/T4 form:
// separate minimal lgkm wait + __builtin_amdgcn_s_barrier() builtin (scheduler
// understands it; no vmcnt drain; counted vmcnt survives across it - that is
// the 8-phase template's core result). edge_async only; all its cross-wave
// deps are LDS (lgkm-covered); ebh stores fire-and-forget.

#define D    128
#define TE   64
#define XS   264   // legacy s_x row stride
#define TE2  32    // async edge tile rows
#define MAXT 40    // max tiles per persistent block (n2 <= 327680)

typedef float  f32x4 __attribute__((ext_vector_type(4)));
typedef _Float16 f16x8 __attribute__((ext_vector_type(8)));

__device__ __forceinline__ unsigned short f2h(float f) {
    union { _Float16 h; unsigned short u; } x;
    x.h = (_Float16)f;
    return x.u;
}

// raw workgroup barrier: LDS-only wait (lgkm), barrier via builtin (no vmcnt
// drain, no schedule pinning). VMEM prefetch loads stay in flight across it.
__device__ __forceinline__ void rbar() {
    asm volatile("s_waitcnt lgkmcnt(0)" ::: "memory");
    __builtin_amdgcn_s_barrier();
}

// ---- weight pack + cnt zero (fused) ----
__global__ __launch_bounds__(256) void pack_zero(
    const float* __restrict__ brW1, const float* __restrict__ brW2,
    const float* __restrict__ sW1,  const float* __restrict__ sW2,
    const float* __restrict__ hW,   unsigned short* __restrict__ Wp,
    int* __restrict__ cnt, int AN)
{
    int p = blockIdx.x * 256 + threadIdx.x;   // 0 .. 262143
    if (p < AN) cnt[p] = 0;
    const float* src; int off, K;
    if (p < 65536)       { src = brW1; off = 0;      K = 256; }
    else if (p < 98304)  { src = brW2; off = 65536;  K = 128; }
    else if (p < 163840) { src = sW1;  off = 98304;  K = 256; }
    else if (p < 196608) { src = sW2;  off = 163840; K = 128; }
    else                 { src = hW;   off = 196608; K = 256; }
    int q = p - off, lvl, r;
    if (K == 256) { lvl = q >> 15; r = q & 32767; }
    else          { lvl = q >> 14; r = q & 16383; }
    int kb = r >> 12, n = (r >> 5) & 127, kk = r & 31;
    Wp[p] = f2h(src[(size_t)lvl * K * 128 + (size_t)(kb * 32 + kk) * 128 + n]);
}

// ================= CSR build (r8) =================

__global__ __launch_bounds__(256) void csr_hist(
    const int* __restrict__ dA, int EA, const int* __restrict__ dB, int EB,
    int* __restrict__ cnt, int AOFFv)
{
    int i = blockIdx.x * 256 + threadIdx.x;
    if (i < EA)               atomicAdd(cnt + dA[i], 1);
    else if (i - EA < EB)     atomicAdd(cnt + AOFFv + dB[i - EA], 1);
}

__global__ __launch_bounds__(256) void csr_scanA(
    const int* __restrict__ cnt, int* __restrict__ inc, int* __restrict__ bsum,
    int nbA, int AOFFv)
{
    __shared__ int lds[256];
    int b = blockIdx.x, t = threadIdx.x;
    int lb, ebase, bs;
    if (b < nbA) { lb = b;       ebase = 0;     bs = lb; }
    else         { lb = b - nbA; ebase = AOFFv; bs = 128 + lb; }
    int idx = ebase + lb * 1024 + t * 4;
    int s0 = cnt[idx], s1 = cnt[idx + 1], s2 = cnt[idx + 2], s3 = cnt[idx + 3];
    int p1 = s0 + s1, p2 = p1 + s2, p3 = p2 + s3;
    lds[t] = p3; __syncthreads();
#pragma unroll
    for (int o = 1; o < 256; o <<= 1) {
        int v = (t >= o) ? lds[t - o] : 0;
        __syncthreads();
        lds[t] += v;
        __syncthreads();
    }
    int ex = lds[t] - p3;
    inc[idx] = ex + s0; inc[idx + 1] = ex + p1; inc[idx + 2] = ex + p2; inc[idx + 3] = ex + p3;
    if (t == 255) bsum[bs] = lds[255];
}

__global__ __launch_bounds__(256) void csr_scanC2(
    const int* __restrict__ cnt, int* __restrict__ inc, const int* __restrict__ bsum,
    int* __restrict__ cursor, int nbA, int nbB, int AOFFv)
{
    __shared__ int lds[256];
    int b = blockIdx.x, t = threadIdx.x;
    int seg = t >> 7, i = t & 127;
    int n = seg ? nbB : nbA;
    lds[t] = (i < n) ? bsum[t] : 0;
    __syncthreads();
#pragma unroll
    for (int o = 1; o < 128; o <<= 1) {
        int v = (i >= o) ? lds[t - o] : 0;
        __syncthreads();
        lds[t] += v;
        __syncthreads();
    }
    int lb, ebase, bs;
    if (b < nbA) { lb = b;       ebase = 0;     bs = lb; }
    else         { lb = b - nbA; ebase = AOFFv; bs = 128 + lb; }
    int carry = (lb > 0) ? lds[bs - 1] : 0;
    int idx = ebase + lb * 1024 + t * 4;
#pragma unroll
    for (int j = 0; j < 4; ++j) {
        int v = inc[idx + j] + carry;
        inc[idx + j] = v;
        cursor[idx + j] = v - cnt[idx + j];
    }
}

__global__ __launch_bounds__(256) void csr_pos(
    const int* __restrict__ dA, int EA, const int* __restrict__ dB, int EB,
    int* __restrict__ cursor, int* __restrict__ posA, int* __restrict__ posB, int AOFFv)
{
    int i = blockIdx.x * 256 + threadIdx.x;
    if (i < EA)           posA[i] = atomicAdd(cursor + dA[i], 1);
    else if (i - EA < EB) posB[i - EA] = atomicAdd(cursor + AOFFv + dB[i - EA], 1);
}

// ================= async persistent edge MLP (raw builtin barriers) =================

__device__ __forceinline__ void ln_relu32(f32x4 acc[4],
    const float* __restrict__ b, const float* __restrict__ g, const float* __restrict__ be,
    float* s_red, float* s_ms, int rb, int cb, int n15, int q, int wcol, int t)
{
#pragma unroll
    for (int ct = 0; ct < 4; ++ct) {
        float bb = b[cb + ct * 16 + n15];
#pragma unroll
        for (int r = 0; r < 4; ++r) acc[ct][r] += bb;
    }
    float sum[4], ss[4];
#pragma unroll
    for (int r = 0; r < 4; ++r) {
        sum[r] = acc[0][r] + acc[1][r] + acc[2][r] + acc[3][r];
        ss[r]  = acc[0][r]*acc[0][r] + acc[1][r]*acc[1][r]
               + acc[2][r]*acc[2][r] + acc[3][r]*acc[3][r];
    }
#pragma unroll
    for (int off = 1; off < 16; off <<= 1) {
#pragma unroll
        for (int r = 0; r < 4; ++r) {
            sum[r] += __shfl_xor(sum[r], off, 64);
            ss[r]  += __shfl_xor(ss[r],  off, 64);
        }
    }
    if (n15 == 0) {
#pragma unroll
        for (int r = 0; r < 4; ++r) {
            int row = rb + q * 4 + r;
            s_red[row * 4 + wcol * 2 + 0] = sum[r];
            s_red[row * 4 + wcol * 2 + 1] = ss[r];
        }
    }
    rbar();
    if (t < TE2) {
        float sm = s_red[t * 4 + 0] + s_red[t * 4 + 2];
        float sq = s_red[t * 4 + 1] + s_red[t * 4 + 3];
        float mean = sm * (1.f / 128.f);
        float var  = sq * (1.f / 128.f) - mean * mean;
        s_ms[t * 2 + 0] = mean;
        s_ms[t * 2 + 1] = rsqrtf(var + 1e-5f);
    }
    rbar();
#pragma unroll
    for (int ct = 0; ct < 4; ++ct) {
        float gg = g[cb + ct * 16 + n15], bb = be[cb + ct * 16 + n15];
#pragma unroll
        for (int r = 0; r < 4; ++r) {
            int row = rb + q * 4 + r;
            float v = (acc[ct][r] - s_ms[row * 2 + 0]) * s_ms[row * 2 + 1] * gg + bb;
            acc[ct][r] = fmaxf(v, 0.f);
        }
    }
}

// x-buffer: [32 rows][512B]; 16B unit u of row r at (u ^ (r&7)). h = units 0..15,
// bond = 16..31. f1/f2: [32][256B], unit u at (u ^ (r&7)). Weights: [kb][512 units],
// unit l (= n*4+q) at l ^ ((n>>1)&3).
template<bool HBF16>
__global__ __launch_bounds__(256, 1) void edge_async(
    const void* __restrict__ hsrc, const float* __restrict__ bond,
    const int* __restrict__ src, const int* __restrict__ dstpos,
    const unsigned short* __restrict__ Wp1g, const unsigned short* __restrict__ Wp2g,
    const float* __restrict__ b1, const float* __restrict__ g1, const float* __restrict__ be1,
    const float* __restrict__ b2, const float* __restrict__ g2, const float* __restrict__ be2,
    unsigned short* __restrict__ ebh, int E, int ntiles, int chunk)
{
    __shared__ unsigned short s_w1[32768];       // 64KB
    __shared__ unsigned short s_w2[16384];       // 32KB
    __shared__ unsigned short s_x[2][8192];      // 2 x 16KB
    __shared__ int   s_meta[MAXT * 64];          // [tile][src 0..31 | dst 32..63]
    __shared__ float s_red[TE2 * 4];
    __shared__ float s_ms[TE2 * 2];

    int t = threadIdx.x;
    int tile0 = blockIdx.x * chunk;
    int myT = ntiles - tile0;
    if (myT > chunk) myT = chunk;

    // ---- prologue: weights + meta -> LDS ----
    {
        const uint4* w1 = (const uint4*)Wp1g;
        for (int u = t; u < 4096; u += 256) {
            int kb = u >> 9, l = u & 511, n = l >> 2;
            *(uint4*)((char*)s_w1 + kb * 8192 + ((l ^ ((n >> 1) & 3)) << 4)) = w1[u];
        }
        const uint4* w2 = (const uint4*)Wp2g;
        for (int u = t; u < 2048; u += 256) {
            int kb = u >> 9, l = u & 511, n = l >> 2;
            *(uint4*)((char*)s_w2 + kb * 8192 + ((l ^ ((n >> 1) & 3)) << 4)) = w2[u];
        }
        for (int x = t; x < myT * 64; x += 256) {
            int ti = x >> 6, r = x & 63;
            int ge = (tile0 + ti) * TE2 + (r & 31);
            int v;
            if (r < 32) v = (ge < E) ? src[ge] : 0;
            else        v = (ge < E) ? dstpos[ge] : -1;
            s_meta[x] = v;
        }
    }
    __syncthreads();   // prologue barrier: full drain is fine (once)
    if (myT <= 0) return;

    int r0  = t >> 5, k4 = t & 31;   // fp32 chunks: rows r0+8j
    int r0h = t >> 4, k8 = t & 15;   // 16B chunks: rows r0h+16j

    // ---- stage tile 0 into buf 0 ----
    {
        if (HBF16) {
            const unsigned short* hp = (const unsigned short*)hsrc;
#pragma unroll
            for (int j = 0; j < 2; ++j) {
                int row = r0h + 16 * j;
                int sv = s_meta[row];
                uint4 v = *(const uint4*)(hp + (size_t)sv * 128 + k8 * 8);
                *(uint4*)((char*)&s_x[0][0] + row * 512 + ((k8 ^ (row & 7)) << 4)) = v;
            }
        } else {
            const float* hp = (const float*)hsrc;
#pragma unroll
            for (int j = 0; j < 4; ++j) {
                int row = r0 + 8 * j;
                int sv = s_meta[row];
                float4 v = *(const float4*)(hp + (size_t)sv * 128 + k4 * 4);
                ushort4 o; o.x = f2h(v.x); o.y = f2h(v.y); o.z = f2h(v.z); o.w = f2h(v.w);
                *(ushort4*)((char*)&s_x[0][0] + row * 512
                            + (((k4 >> 1) ^ (row & 7)) << 4) + (k4 & 1) * 8) = o;
            }
        }
#pragma unroll
        for (int j = 0; j < 4; ++j) {
            int row = r0 + 8 * j;
            int ge = tile0 * TE2 + row;
            float4 v = make_float4(0, 0, 0, 0);
            if (ge < E) v = *(const float4*)(bond + (size_t)ge * 128 + k4 * 4);
            ushort4 o; o.x = f2h(v.x); o.y = f2h(v.y); o.z = f2h(v.z); o.w = f2h(v.w);
            *(ushort4*)((char*)&s_x[0][0] + row * 512
                        + (((16 + (k4 >> 1)) ^ (row & 7)) << 4) + (k4 & 1) * 8) = o;
        }
    }
    __syncthreads();   // tile-0 stage: full drain fine (once)

    int lane = t & 63, w = t >> 6;
    int n15 = lane & 15, q = lane >> 4;
    int rb = (w & 1) * 16, cb = (w >> 1) * 64, wcol = w >> 1;

    int c = 0;
    for (int i = 0; i < myT; ++i) {
        // ---- issue next-tile loads into registers; raw barriers keep them in flight ----
        bool hasN = (i + 1 < myT);
        uint4  nh16[2]; float4 nh32[4]; float4 nb[4];
        if (hasN) {
            int mt = i + 1, tb = (tile0 + mt) * TE2;
            if (HBF16) {
                const unsigned short* hp = (const unsigned short*)hsrc;
#pragma unroll
                for (int j = 0; j < 2; ++j) {
                    int row = r0h + 16 * j;
                    int sv = s_meta[mt * 64 + row];
                    nh16[j] = *(const uint4*)(hp + (size_t)sv * 128 + k8 * 8);
                }
            } else {
                const float* hp = (const float*)hsrc;
#pragma unroll
                for (int j = 0; j < 4; ++j) {
                    int row = r0 + 8 * j;
                    int sv = s_meta[mt * 64 + row];
                    nh32[j] = *(const float4*)(hp + (size_t)sv * 128 + k4 * 4);
                }
            }
#pragma unroll
            for (int j = 0; j < 4; ++j) {
                int row = r0 + 8 * j, ge = tb + row;
                nb[j] = make_float4(0, 0, 0, 0);
                if (ge < E) nb[j] = *(const float4*)(bond + (size_t)ge * 128 + k4 * 4);
            }
        }

        const unsigned short* xb = &s_x[c][0];
        unsigned short* f1b = (unsigned short*)&s_x[c ^ 1][0];   // alias idle buffer
        unsigned short* f2b = f1b + 4096;

        // ---- GEMM1: [h | bond] x Wp1 (LDS weights) ----
        f32x4 acc[4];
        f32x4 zero = {0.f, 0.f, 0.f, 0.f};
#pragma unroll
        for (int ct = 0; ct < 4; ++ct) acc[ct] = zero;
#pragma unroll
        for (int kb = 0; kb < 8; ++kb) {
            f16x8 af = *(const f16x8*)((const char*)xb + (rb + n15) * 512
                                       + (((kb * 4 + q) ^ (n15 & 7)) << 4));
#pragma unroll
            for (int ct = 0; ct < 4; ++ct) {
                int n = cb + ct * 16 + n15, l = n * 4 + q;
                f16x8 bf = *(const f16x8*)((const char*)s_w1 + kb * 8192
                                           + ((l ^ ((n >> 1) & 3)) << 4));
                acc[ct] = __builtin_amdgcn_mfma_f32_16x16x32_f16(af, bf, acc[ct], 0, 0, 0);
            }
        }
        ln_relu32(acc, b1, g1, be1, s_red, s_ms, rb, cb, n15, q, wcol, t);
#pragma unroll
        for (int ct = 0; ct < 4; ++ct)
#pragma unroll
            for (int r = 0; r < 4; ++r) {
                int row = rb + q * 4 + r, col = cb + ct * 16 + n15;
                *(unsigned short*)((char*)f1b + row * 256
                                   + ((col * 2) ^ ((row & 7) << 4))) = f2h(acc[ct][r]);
            }
        rbar();

        // ---- GEMM2: f1 x Wp2 ----
#pragma unroll
        for (int ct = 0; ct < 4; ++ct) acc[ct] = zero;
#pragma unroll
        for (int kb = 0; kb < 4; ++kb) {
            f16x8 af = *(const f16x8*)((const char*)f1b + (rb + n15) * 256
                                       + (((kb * 4 + q) ^ (n15 & 7)) << 4));
#pragma unroll
            for (int ct = 0; ct < 4; ++ct) {
                int n = cb + ct * 16 + n15, l = n * 4 + q;
                f16x8 bf = *(const f16x8*)((const char*)s_w2 + kb * 8192
                                           + ((l ^ ((n >> 1) & 3)) << 4));
                acc[ct] = __builtin_amdgcn_mfma_f32_16x16x32_f16(af, bf, acc[ct], 0, 0, 0);
            }
        }
        ln_relu32(acc, b2, g2, be2, s_red, s_ms, rb, cb, n15, q, wcol, t);
#pragma unroll
        for (int ct = 0; ct < 4; ++ct)
#pragma unroll
            for (int r = 0; r < 4; ++r) {
                int row = rb + q * 4 + r, col = cb + ct * 16 + n15;
                *(unsigned short*)((char*)f2b + row * 256
                                   + ((col * 2) ^ ((row & 7) << 4))) = f2h(acc[ct][r]);
            }
        rbar();

        // ---- coalesced row stores (fire-and-forget) to dst-sorted slots ----
#pragma unroll
        for (int j = 0; j < 2; ++j) {
            int row = r0h + 16 * j;
            int p = s_meta[i * 64 + 32 + row];
            if (p >= 0) {
                uint4 v = *(const uint4*)((const char*)f2b + row * 256
                                          + ((k8 ^ (row & 7)) << 4));
                *(uint4*)(ebh + (size_t)p * 128 + k8 * 8) = v;
            }
        }
        rbar();   // all f1/f2/x LDS reads done -> safe to overwrite alias buffer

        // ---- write prefetched tile i+1 into the idle buffer ----
        // (compiler inserts counted vmcnt waits for nh/nb here; latency covered
        //  by GEMM1+LN1+GEMM2+LN2 above)
        if (hasN) {
            unsigned short* dstb = (unsigned short*)&s_x[c ^ 1][0];
            if (HBF16) {
#pragma unroll
                for (int j = 0; j < 2; ++j) {
                    int row = r0h + 16 * j;
                    *(uint4*)((char*)dstb + row * 512 + ((k8 ^ (row & 7)) << 4)) = nh16[j];
                }
            } else {
#pragma unroll
                for (int j = 0; j < 4; ++j) {
                    int row = r0 + 8 * j;
                    ushort4 o;
                    o.x = f2h(nh32[j].x); o.y = f2h(nh32[j].y);
                    o.z = f2h(nh32[j].z); o.w = f2h(nh32[j].w);
                    *(ushort4*)((char*)dstb + row * 512
                                + (((k4 >> 1) ^ (row & 7)) << 4) + (k4 & 1) * 8) = o;
                }
            }
#pragma unroll
            for (int j = 0; j < 4; ++j) {
                int row = r0 + 8 * j;
                ushort4 o;
                o.x = f2h(nb[j].x); o.y = f2h(nb[j].y); o.z = f2h(nb[j].z); o.w = f2h(nb[j].w);
                *(ushort4*)((char*)dstb + row * 512
                            + (((16 + (k4 >> 1)) ^ (row & 7)) << 4) + (k4 & 1) * 8) = o;
            }
        }
        rbar();
        c ^= 1;
    }
}

// ================= MLP kernels (r8 / fallback) =================

template<int KB>
__device__ __forceinline__ void gemm_f16(const unsigned short* s_in, int stride,
    const unsigned short* __restrict__ Wp, int rb, int cb, int n15, int q, f32x4 acc[2][4])
{
    f32x4 zero = {0.f, 0.f, 0.f, 0.f};
#pragma unroll
    for (int m = 0; m < 2; ++m)
#pragma unroll
        for (int ct = 0; ct < 4; ++ct) acc[m][ct] = zero;
#pragma unroll
    for (int kb = 0; kb < KB; ++kb) {
        f16x8 af0 = *(const f16x8*)(s_in + (rb + n15) * stride + kb * 32 + q * 8);
        f16x8 af1 = *(const f16x8*)(s_in + (rb + 16 + n15) * stride + kb * 32 + q * 8);
        const unsigned short* wb = Wp + (size_t)kb * 4096 + q * 8;
#pragma unroll
        for (int ct = 0; ct < 4; ++ct) {
            f16x8 bf = *(const f16x8*)(wb + (cb + ct * 16 + n15) * 32);
            acc[0][ct] = __builtin_amdgcn_mfma_f32_16x16x32_f16(af0, bf, acc[0][ct], 0, 0, 0);
            acc[1][ct] = __builtin_amdgcn_mfma_f32_16x16x32_f16(af1, bf, acc[1][ct], 0, 0, 0);
        }
    }
}

__device__ __forceinline__ void ln_relu(f32x4 acc[2][4],
    const float* __restrict__ b, const float* __restrict__ g, const float* __restrict__ be,
    float* s_red, float* s_ms, int rb, int cb, int n15, int q, int wcol, int t)
{
#pragma unroll
    for (int ct = 0; ct < 4; ++ct) {
        float bb = b[cb + ct * 16 + n15];
#pragma unroll
        for (int m = 0; m < 2; ++m)
#pragma unroll
            for (int r = 0; r < 4; ++r) acc[m][ct][r] += bb;
    }
    float sum[2][4], ss[2][4];
#pragma unroll
    for (int m = 0; m < 2; ++m)
#pragma unroll
        for (int r = 0; r < 4; ++r) {
            sum[m][r] = acc[m][0][r] + acc[m][1][r] + acc[m][2][r] + acc[m][3][r];
            ss[m][r]  = acc[m][0][r]*acc[m][0][r] + acc[m][1][r]*acc[m][1][r]
                      + acc[m][2][r]*acc[m][2][r] + acc[m][3][r]*acc[m][3][r];
        }
#pragma unroll
    for (int off = 1; off < 16; off <<= 1) {
#pragma unroll
        for (int m = 0; m < 2; ++m)
#pragma unroll
            for (int r = 0; r < 4; ++r) {
                sum[m][r] += __shfl_xor(sum[m][r], off, 64);
                ss[m][r]  += __shfl_xor(ss[m][r],  off, 64);
            }
    }
    if (n15 == 0) {
#pragma unroll
        for (int m = 0; m < 2; ++m)
#pragma unroll
            for (int r = 0; r < 4; ++r) {
                int row = rb + m * 16 + q * 4 + r;
                s_red[row * 4 + wcol * 2 + 0] = sum[m][r];
                s_red[row * 4 + wcol * 2 + 1] = ss[m][r];
            }
    }
    __syncthreads();
    if (t < TE) {
        float sm = s_red[t * 4 + 0] + s_red[t * 4 + 2];
        float sq = s_red[t * 4 + 1] + s_red[t * 4 + 3];
        float mean = sm * (1.f / 128.f);
        float var  = sq * (1.f / 128.f) - mean * mean;
        s_ms[t * 2 + 0] = mean;
        s_ms[t * 2 + 1] = rsqrtf(var + 1e-5f);
    }
    __syncthreads();
#pragma unroll
    for (int ct = 0; ct < 4; ++ct) {
        float gg = g[cb + ct * 16 + n15], bb = be[cb + ct * 16 + n15];
#pragma unroll
        for (int m = 0; m < 2; ++m)
#pragma unroll
            for (int r = 0; r < 4; ++r) {
                int row = rb + m * 16 + q * 4 + r;
                float v = (acc[m][ct][r] - s_ms[row * 2 + 0]) * s_ms[row * 2 + 1] * gg + bb;
                acc[m][ct][r] = fmaxf(v, 0.f);
            }
    }
}

template<bool HBF16, bool CSR>
__global__ __launch_bounds__(256, 4) void edge_mlp(
    const void* __restrict__ hsrc, const float* __restrict__ bond,
    const int* __restrict__ src, const int* __restrict__ dstpos,
    const unsigned short* __restrict__ Wp1, const unsigned short* __restrict__ Wp2,
    const float* __restrict__ b1, const float* __restrict__ g1, const float* __restrict__ be1,
    const float* __restrict__ b2, const float* __restrict__ g2, const float* __restrict__ be2,
    float* __restrict__ agg, unsigned short* __restrict__ ebh, int E)
{
    __shared__ unsigned short s_x[TE * XS];
    __shared__ float s_red[TE * 4];
    __shared__ float s_ms[TE * 2];
    __shared__ int s_src[TE], s_idx[TE];
    unsigned short* s_y = s_x + 128;

    int t = threadIdx.x, eb = blockIdx.x * TE;
    if (t < TE) {
        int ge = eb + t;
        s_src[t] = (ge < E) ? src[ge] : -1;
        s_idx[t] = (ge < E) ? dstpos[ge] : -1;
    }
    __syncthreads();

    if (HBF16) {
        const unsigned short* hp = (const unsigned short*)hsrc;
        for (int c = t; c < TE * 16; c += 256) {
            int row = c >> 4, k8 = c & 15;
            int s = s_src[row];
            uint4 v = make_uint4(0, 0, 0, 0);
            if (s >= 0) v = *(const uint4*)(hp + (size_t)s * 128 + k8 * 8);
            *(uint4*)(s_x + row * XS + k8 * 8) = v;
        }
    } else {
        const float* hp = (const float*)hsrc;
        for (int c = t; c < TE * 32; c += 256) {
            int row = c >> 5, k4 = c & 31;
            int s = s_src[row];
            float4 v = make_float4(0, 0, 0, 0);
            if (s >= 0) v = *(const float4*)(hp + (size_t)s * 128 + k4 * 4);
            ushort4 o; o.x = f2h(v.x); o.y = f2h(v.y); o.z = f2h(v.z); o.w = f2h(v.w);
            *(ushort4*)(s_x + row * XS + k4 * 4) = o;
        }
    }
    for (int c = t; c < TE * 32; c += 256) {
        int row = c >> 5, k4 = c & 31;
        int ge = eb + row;
        float4 v = make_float4(0, 0, 0, 0);
        if (ge < E) v = *(const float4*)(bond + (size_t)ge * 128 + k4 * 4);
        ushort4 o; o.x = f2h(v.x); o.y = f2h(v.y); o.z = f2h(v.z); o.w = f2h(v.w);
        *(ushort4*)(s_x + row * XS + 128 + k4 * 4) = o;
    }
    __syncthreads();

    int l = t & 63, w = t >> 6;
    int n15 = l & 15, q = l >> 4;
    int rb = (w & 1) * 32, cb = (w >> 1) * 64, wcol = w >> 1;

    f32x4 acc[2][4];
    gemm_f16<8>(s_x, XS, Wp1, rb, cb, n15, q, acc);
    ln_relu(acc, b1, g1, be1, s_red, s_ms, rb, cb, n15, q, wcol, t);
#pragma unroll
    for (int m = 0; m < 2; ++m)
#pragma unroll
        for (int ct = 0; ct < 4; ++ct)
#pragma unroll
            for (int r = 0; r < 4; ++r)
                s_y[(rb + m * 16 + q * 4 + r) * XS + cb + ct * 16 + n15] = f2h(acc[m][ct][r]);
    __syncthreads();
    gemm_f16<4>(s_y, XS, Wp2, rb, cb, n15, q, acc);
    ln_relu(acc, b2, g2, be2, s_red, s_ms, rb, cb, n15, q, wcol, t);

    if (CSR) {
#pragma unroll
        for (int m = 0; m < 2; ++m)
#pragma unroll
            for (int ct = 0; ct < 4; ++ct)
#pragma unroll
                for (int r = 0; r < 4; ++r)
                    s_x[(rb + m * 16 + q * 4 + r) * XS + cb + ct * 16 + n15] = f2h(acc[m][ct][r]);
        __syncthreads();
        for (int c = t; c < TE * 16; c += 256) {
            int row = c >> 4, k8 = c & 15;
            int p = s_idx[row];
            if (p >= 0)
                *(uint4*)(ebh + (size_t)p * 128 + k8 * 8) =
                    *(const uint4*)(s_x + row * XS + k8 * 8);
        }
    } else {
#pragma unroll
        for (int m = 0; m < 2; ++m)
#pragma unroll
            for (int ct = 0; ct < 4; ++ct)
#pragma unroll
                for (int r = 0; r < 4; ++r) {
                    int row = rb + m * 16 + q * 4 + r;
                    int gd = s_idx[row];
                    if (gd >= 0)
                        atomicAdd(agg + (size_t)gd * D + cb + ct * 16 + n15, acc[m][ct][r]);
                }
    }
}

template<bool OUT_F16, bool CSR>
__global__ __launch_bounds__(256, 4) void node_mlp(
    const float* __restrict__ ax, const float* __restrict__ agg,
    const int* __restrict__ inc, const unsigned short* __restrict__ ebh,
    const unsigned short* __restrict__ Wp1, const unsigned short* __restrict__ Wp2,
    const unsigned short* __restrict__ Wp3,
    const float* __restrict__ b1, const float* __restrict__ g1, const float* __restrict__ be1,
    const float* __restrict__ b2, const float* __restrict__ g2, const float* __restrict__ be2,
    const float* __restrict__ b3, const float* __restrict__ g3, const float* __restrict__ be3,
    void* __restrict__ out, int N)
{
    __shared__ unsigned short s_x[TE * XS];
    __shared__ float s_red[TE * 4];
    __shared__ float s_ms[TE * 2];
    __shared__ int s_beg[TE], s_end[TE];
    unsigned short* s_y = s_x + 128;

    int t = threadIdx.x, nb = blockIdx.x * TE;

    if (CSR && t < TE) {
        int gr = nb + t, b0 = 0, e0 = 0;
        if (gr < N) { e0 = inc[gr]; b0 = (gr == 0) ? 0 : inc[gr - 1]; }
        s_beg[t] = b0; s_end[t] = e0;
    }

    for (int c = t; c < TE * 32; c += 256) {
        int row = c >> 5, k4 = c & 31;
        int gr = nb + row;
        float4 v = make_float4(0, 0, 0, 0);
        if (gr < N) v = *(const float4*)(ax + (size_t)gr * 128 + k4 * 4);
        ushort4 o; o.x = f2h(v.x); o.y = f2h(v.y); o.z = f2h(v.z); o.w = f2h(v.w);
        *(ushort4*)(s_x + row * XS + k4 * 4) = o;
    }

    if (CSR) {
        __syncthreads();
        int r = t >> 2, s4 = t & 3;
        float a[32];
#pragma unroll
        for (int k = 0; k < 32; ++k) a[k] = 0.f;
        int jb = s_beg[r], je = s_end[r];
        int j = jb;
        for (; j + 2 <= je; j += 2) {
            const unsigned short* rp0 = ebh + (size_t)j * 128 + s4 * 32;
            const unsigned short* rp1 = rp0 + 128;
            f16x8 a0 = *(const f16x8*)rp0;
            f16x8 a1 = *(const f16x8*)(rp0 + 8);
            f16x8 a2 = *(const f16x8*)(rp0 + 16);
            f16x8 a3 = *(const f16x8*)(rp0 + 24);
            f16x8 b0 = *(const f16x8*)rp1;
            f16x8 b1v = *(const f16x8*)(rp1 + 8);
            f16x8 b2v = *(const f16x8*)(rp1 + 16);
            f16x8 b3v = *(const f16x8*)(rp1 + 24);
#pragma unroll
            for (int k = 0; k < 8; ++k) {
                a[k]      += (float)a0[k];
                a[8 + k]  += (float)a1[k];
                a[16 + k] += (float)a2[k];
                a[24 + k] += (float)a3[k];
            }
#pragma unroll
            for (int k = 0; k < 8; ++k) {
                a[k]      += (float)b0[k];
                a[8 + k]  += (float)b1v[k];
                a[16 + k] += (float)b2v[k];
                a[24 + k] += (float)b3v[k];
            }
        }
        if (j < je) {
            const unsigned short* rp = ebh + (size_t)j * 128 + s4 * 32;
            f16x8 v0 = *(const f16x8*)rp;
            f16x8 v1 = *(const f16x8*)(rp + 8);
            f16x8 v2 = *(const f16x8*)(rp + 16);
            f16x8 v3 = *(const f16x8*)(rp + 24);
#pragma unroll
            for (int k = 0; k < 8; ++k) {
                a[k]      += (float)v0[k];
                a[8 + k]  += (float)v1[k];
                a[16 + k] += (float)v2[k];
                a[24 + k] += (float)v3[k];
            }
        }
        unsigned short* op = s_x + r * XS + 128 + s4 * 32;
#pragma unroll
        for (int blk = 0; blk < 4; ++blk) {
            f16x8 h;
#pragma unroll
            for (int k = 0; k < 8; ++k) h[k] = (_Float16)a[blk * 8 + k];
            *(f16x8*)(op + blk * 8) = h;
        }
    } else {
        for (int c = t; c < TE * 32; c += 256) {
            int row = c >> 5, k4 = c & 31;
            int gr = nb + row;
            float4 v = make_float4(0, 0, 0, 0);
            if (gr < N) v = *(const float4*)(agg + (size_t)gr * 128 + k4 * 4);
            ushort4 o; o.x = f2h(v.x); o.y = f2h(v.y); o.z = f2h(v.z); o.w = f2h(v.w);
            *(ushort4*)(s_x + row * XS + 128 + k4 * 4) = o;
        }
    }
    __syncthreads();

    int l = t & 63, w = t >> 6;
    int n15 = l & 15, q = l >> 4;
    int rb = (w & 1) * 32, cb = (w >> 1) * 64, wcol = w >> 1;

    f32x4 acc[2][4];
    gemm_f16<8>(s_x, XS, Wp1, rb, cb, n15, q, acc);
    ln_relu(acc, b1, g1, be1, s_red, s_ms, rb, cb, n15, q, wcol, t);
#pragma unroll
    for (int m = 0; m < 2; ++m)
#pragma unroll
        for (int ct = 0; ct < 4; ++ct)
#pragma unroll
            for (int r = 0; r < 4; ++r)
                s_y[(rb + m * 16 + q * 4 + r) * XS + cb + ct * 16 + n15] = f2h(acc[m][ct][r]);
    __syncthreads();
    gemm_f16<4>(s_y, XS, Wp2, rb, cb, n15, q, acc);
    ln_relu(acc, b2, g2, be2, s_red, s_ms, rb, cb, n15, q, wcol, t);
#pragma unroll
    for (int m = 0; m < 2; ++m)
#pragma unroll
        for (int ct = 0; ct < 4; ++ct)
#pragma unroll
            for (int r = 0; r < 4; ++r)
                s_x[(rb + m * 16 + q * 4 + r) * XS + 128 + cb + ct * 16 + n15] = f2h(acc[m][ct][r]);
    __syncthreads();
    gemm_f16<8>(s_x, XS, Wp3, rb, cb, n15, q, acc);
    ln_relu(acc, b3, g3, be3, s_red, s_ms, rb, cb, n15, q, wcol, t);

#pragma unroll
    for (int m = 0; m < 2; ++m)
#pragma unroll
        for (int ct = 0; ct < 4; ++ct)
#pragma unroll
            for (int r = 0; r < 4; ++r) {
                int row = rb + m * 16 + q * 4 + r;
                int gr = nb + row;
                int col = cb + ct * 16 + n15;
                if (gr < N) {
                    if (OUT_F16)
                        ((unsigned short*)out)[(size_t)gr * D + col] = f2h(acc[m][ct][r]);
                    else
                        ((float*)out)[(size_t)gr * D + col] = acc[m][ct][r];
                }
            }
}

extern "C" void kernel_launch(void* const* d_in, const int* in_sizes, int n_in,
                              void* d_out, int out_size, void* d_ws, size_t ws_size,
                              hipStream_t stream)
{
    const float* h2   = (const float*)d_in[0];
    const float* ax1  = (const float*)d_in[1];
    const float* ax0  = (const float*)d_in[2];
    const float* bx2  = (const float*)d_in[3];
    const float* bx1  = (const float*)d_in[4];
    const float* brW1 = (const float*)d_in[5];
    const float* brb1 = (const float*)d_in[6];
    const float* brg1 = (const float*)d_in[7];
    const float* brbe1= (const float*)d_in[8];
    const float* brW2 = (const float*)d_in[9];
    const float* brb2 = (const float*)d_in[10];
    const float* brg2 = (const float*)d_in[11];
    const float* brbe2= (const float*)d_in[12];
    const float* sW1  = (const float*)d_in[13];
    const float* sb1  = (const float*)d_in[14];
    const float* sg1  = (const float*)d_in[15];
    const float* sbe1 = (const float*)d_in[16];
    const float* sW2  = (const float*)d_in[17];
    const float* sb2  = (const float*)d_in[18];
    const float* sg2  = (const float*)d_in[19];
    const float* sbe2 = (const float*)d_in[20];
    const float* hW   = (const float*)d_in[21];
    const float* hb   = (const float*)d_in[22];
    const float* hg   = (const float*)d_in[23];
    const float* hbe  = (const float*)d_in[24];
    const int*   src2 = (const int*)d_in[25];
    const int*   dst2 = (const int*)d_in[26];
    const int*   src1 = (const int*)d_in[27];
    const int*   dst1 = (const int*)d_in[28];

    int n2 = in_sizes[0] / D;
    int n1 = in_sizes[1] / D;
    int n0 = in_sizes[2] / D;

    unsigned short* Wp = (unsigned short*)d_ws;   // 262144 fp16 = 512 KB

    const unsigned short* pBr1[2] = { Wp + 0,      Wp + 32768 };
    const unsigned short* pBr2[2] = { Wp + 65536,  Wp + 65536  + 16384 };
    const unsigned short* pS1 [2] = { Wp + 98304,  Wp + 98304  + 32768 };
    const unsigned short* pS2 [2] = { Wp + 163840, Wp + 163840 + 16384 };
    const unsigned short* pH  [2] = { Wp + 196608, Wp + 196608 + 32768 };

    // ---- workspace layout ----
    int nbA = (n1 + 1023) / 1024, nbB = (n0 + 1023) / 1024;
    int AOFFv = nbA * 1024;
    int AN = AOFFv + nbB * 1024;
    auto al = [](size_t x) { return (x + 255) & ~(size_t)255; };
    size_t o = 524288;
    size_t cnt_o  = o; o = al(o + (size_t)AN * 4);
    size_t inc_o  = o; o = al(o + (size_t)AN * 4);
    size_t cur_o  = o; o = al(o + (size_t)AN * 4);
    size_t bsum_o = o; o = al(o + 1024);
    size_t posA_o = o; o = al(o + (size_t)n2 * 4);
    size_t posB_o = o; o = al(o + (size_t)n1 * 4);
    size_t h1_o   = o; o = al(o + (size_t)n1 * 256);
    size_t ebh_o  = o; o = al(o + (size_t)n2 * 256);
    size_t o_csr  = o;
    bool use_csr = (nbA <= 128) && (nbB <= 128) && (ws_size >= o_csr);

    int t2e = (n2 + TE - 1) / TE, t1e = (n1 + TE - 1) / TE;
    int t1n = (n1 + TE - 1) / TE, t0n = (n0 + TE - 1) / TE;

    if (use_csr) {
        int*            cnt    = (int*)((char*)d_ws + cnt_o);
        int*            inc    = (int*)((char*)d_ws + inc_o);
        int*            cursor = (int*)((char*)d_ws + cur_o);
        int*            bsum   = (int*)((char*)d_ws + bsum_o);
        int*            posA   = (int*)((char*)d_ws + posA_o);
        int*            posB   = (int*)((char*)d_ws + posB_o);
        unsigned short* h1     = (unsigned short*)((char*)d_ws + h1_o);
        unsigned short* ebh    = (unsigned short*)((char*)d_ws + ebh_o);

        // ---- setup: 5 dispatches ----
        int EG = (n2 + n1 + 255) / 256;
        pack_zero<<<dim3(1024), dim3(256), 0, stream>>>(brW1, brW2, sW1, sW2, hW, Wp, cnt, AN);
        csr_hist  <<<dim3(EG),        dim3(256), 0, stream>>>(dst2, n2, dst1, n1, cnt, AOFFv);
        csr_scanA <<<dim3(nbA + nbB), dim3(256), 0, stream>>>(cnt, inc, bsum, nbA, AOFFv);
        csr_scanC2<<<dim3(nbA + nbB), dim3(256), 0, stream>>>(cnt, inc, bsum, cursor, nbA, nbB, AOFFv);
        csr_pos   <<<dim3(EG),        dim3(256), 0, stream>>>(dst2, n2, dst1, n1, cursor, posA, posB, AOFFv);

        // async-edge tiling (level 2 only)
        int tiles2 = (n2 + TE2 - 1) / TE2, chunk2 = (tiles2 + 255) / 256;
        bool asy2 = (chunk2 <= MAXT);

        // ---- iteration 0 (level 2 -> 1) ----
        if (asy2)
            edge_async<false><<<dim3(256), dim3(256), 0, stream>>>(
                h2, bx2, src2, posA, pBr1[0], pBr2[0],
                brb1, brg1, brbe1, brb2, brg2, brbe2, ebh, n2, tiles2, chunk2);
        else
            edge_mlp<false, true><<<dim3(t2e), dim3(256), 0, stream>>>(
                h2, bx2, src2, posA, pBr1[0], pBr2[0],
                brb1, brg1, brbe1, brb2, brg2, brbe2, nullptr, ebh, n2);
        node_mlp<true, true><<<dim3(t1n), dim3(256), 0, stream>>>(
            ax1, nullptr, inc, ebh, pS1[0], pS2[0], pH[0],
            sb1, sg1, sbe1, sb2, sg2, sbe2, hb, hg, hbe, h1, n1);

        // ---- iteration 1 (level 1 -> 0) ----
        edge_mlp<true, true><<<dim3(t1e), dim3(256), 0, stream>>>(
            h1, bx1, src1, posB, pBr1[1], pBr2[1],
            brb1 + D, brg1 + D, brbe1 + D, brb2 + D, brg2 + D, brbe2 + D, nullptr, ebh, n1);
        node_mlp<false, true><<<dim3(t0n), dim3(256), 0, stream>>>(
            ax0, nullptr, inc + AOFFv, ebh, pS1[1], pS2[1], pH[1],
            sb1 + D, sg1 + D, sbe1 + D, sb2 + D, sg2 + D, sbe2 + D,
            hb + D, hg + D, hbe + D, d_out, n0);
    } else {
        // fallback: atomic-aggregation path
        float*          agg = (float*)((char*)d_ws + 524288);
        unsigned short* h1  = (unsigned short*)(agg + (size_t)n1 * D);

        pack_zero<<<dim3(1024), dim3(256), 0, stream>>>(brW1, brW2, sW1, sW2, hW, Wp, nullptr, 0);

        hipMemsetAsync(agg, 0, (size_t)n1 * D * sizeof(float), stream);
        edge_mlp<false, false><<<dim3(t2e), dim3(256), 0, stream>>>(
            h2, bx2, src2, dst2, pBr1[0], pBr2[0],
            brb1, brg1, brbe1, brb2, brg2, brbe2, agg, nullptr, n2);
        node_mlp<true, false><<<dim3(t1n), dim3(256), 0, stream>>>(
            ax1, agg, nullptr, nullptr, pS1[0], pS2[0], pH[0],
            sb1, sg1, sbe1, sb2, sg2, sbe2, hb, hg, hbe, h1, n1);

        hipMemsetAsync(agg, 0, (size_t)n0 * D * sizeof(float), stream);
        edge_mlp<true, false><<<dim3(t1e), dim3(256), 0, stream>>>(
            h1, bx1, src1, dst1, pBr1[1], pBr2[1],
            brb1 + D, brg1 + D, brbe1 + D, brb2 + D, brg2 + D, brbe2 + D, agg, nullptr, n1);
        node_mlp<false, false><<<dim3(t0n), dim3(256), 0, stream>>>(
            ax0, agg, nullptr, nullptr, pS1[1], pS2[1], pH[1],
            sb1 + D, sg1 + D, sbe1 + D, sb2 + D, sg2 + D, sbe2 + D,
            hb + D, hg + D, hbe + D, d_out, n0);
    }
}

// Round 13
// 653.233 us; speedup vs baseline: 1.0646x; 1.0646x over previous
//
#include <hip/hip_runtime.h>

// TPF encoder, MFMA fp16, CSR aggregation. r13 = r11 verbatim (measured best,
// 659.4us) - reverting the r12 raw-barrier experiment.
//
// Final ledger of the edge-kernel ladder:
//   r0  baseline (atomics, 32-row tiles)          edge2=251us  total 701
//   r2  CSR sort-by-dst (no float atomics)        edge2=200    total 716
//   r3  TE=64 tiles, 2x MFMA/weight-load          edge2=187    total 683
//   r8  setup 7->5 dispatches, segsum unroll      edge2=188    total 675.7
//   r9  edge_async: persistent 1 blk/CU, ALL
//       weights LDS-resident, reg prefetch,
//       __syncthreads                             edge2=173
//   r11 = r9 edge_async (L2) + r8 rest            edge2=172    total 659.4  <-- THIS
//   r10/r12 raw-barrier variants of edge_async    edge2=220/207 (regressed;
//       "memory"-clobbered asm barriers destroy the compiler's LDS scheduling -
//       worse than the vmcnt drain they remove. Reverted.)
// Probes (r6): sequential-gather == random-gather; no-weight == full -> the
// kernel is latency-floor-bound, not gather-randomness- or weight-load-bound.
// Occupancy (r1), barriers (r5), tile size (r3), reg-prefetch-without-LDS-
// weights (r4, spilled) all ablated null.

#define D    128
#define TE   64
#define XS   264   // legacy s_x row stride
#define TE2  32    // async edge tile rows
#define MAXT 40    // max tiles per persistent block (n2 <= 327680)

typedef float  f32x4 __attribute__((ext_vector_type(4)));
typedef _Float16 f16x8 __attribute__((ext_vector_type(8)));

__device__ __forceinline__ unsigned short f2h(float f) {
    union { _Float16 h; unsigned short u; } x;
    x.h = (_Float16)f;
    return x.u;
}

// ---- weight pack + cnt zero (fused) ----
__global__ __launch_bounds__(256) void pack_zero(
    const float* __restrict__ brW1, const float* __restrict__ brW2,
    const float* __restrict__ sW1,  const float* __restrict__ sW2,
    const float* __restrict__ hW,   unsigned short* __restrict__ Wp,
    int* __restrict__ cnt, int AN)
{
    int p = blockIdx.x * 256 + threadIdx.x;   // 0 .. 262143
    if (p < AN) cnt[p] = 0;
    const float* src; int off, K;
    if (p < 65536)       { src = brW1; off = 0;      K = 256; }
    else if (p < 98304)  { src = brW2; off = 65536;  K = 128; }
    else if (p < 163840) { src = sW1;  off = 98304;  K = 256; }
    else if (p < 196608) { src = sW2;  off = 163840; K = 128; }
    else                 { src = hW;   off = 196608; K = 256; }
    int q = p - off, lvl, r;
    if (K == 256) { lvl = q >> 15; r = q & 32767; }
    else          { lvl = q >> 14; r = q & 16383; }
    int kb = r >> 12, n = (r >> 5) & 127, kk = r & 31;
    Wp[p] = f2h(src[(size_t)lvl * K * 128 + (size_t)(kb * 32 + kk) * 128 + n]);
}

// ================= CSR build (r8) =================

__global__ __launch_bounds__(256) void csr_hist(
    const int* __restrict__ dA, int EA, const int* __restrict__ dB, int EB,
    int* __restrict__ cnt, int AOFFv)
{
    int i = blockIdx.x * 256 + threadIdx.x;
    if (i < EA)               atomicAdd(cnt + dA[i], 1);
    else if (i - EA < EB)     atomicAdd(cnt + AOFFv + dB[i - EA], 1);
}

__global__ __launch_bounds__(256) void csr_scanA(
    const int* __restrict__ cnt, int* __restrict__ inc, int* __restrict__ bsum,
    int nbA, int AOFFv)
{
    __shared__ int lds[256];
    int b = blockIdx.x, t = threadIdx.x;
    int lb, ebase, bs;
    if (b < nbA) { lb = b;       ebase = 0;     bs = lb; }
    else         { lb = b - nbA; ebase = AOFFv; bs = 128 + lb; }
    int idx = ebase + lb * 1024 + t * 4;
    int s0 = cnt[idx], s1 = cnt[idx + 1], s2 = cnt[idx + 2], s3 = cnt[idx + 3];
    int p1 = s0 + s1, p2 = p1 + s2, p3 = p2 + s3;
    lds[t] = p3; __syncthreads();
#pragma unroll
    for (int o = 1; o < 256; o <<= 1) {
        int v = (t >= o) ? lds[t - o] : 0;
        __syncthreads();
        lds[t] += v;
        __syncthreads();
    }
    int ex = lds[t] - p3;
    inc[idx] = ex + s0; inc[idx + 1] = ex + p1; inc[idx + 2] = ex + p2; inc[idx + 3] = ex + p3;
    if (t == 255) bsum[bs] = lds[255];
}

__global__ __launch_bounds__(256) void csr_scanC2(
    const int* __restrict__ cnt, int* __restrict__ inc, const int* __restrict__ bsum,
    int* __restrict__ cursor, int nbA, int nbB, int AOFFv)
{
    __shared__ int lds[256];
    int b = blockIdx.x, t = threadIdx.x;
    int seg = t >> 7, i = t & 127;
    int n = seg ? nbB : nbA;
    lds[t] = (i < n) ? bsum[t] : 0;
    __syncthreads();
#pragma unroll
    for (int o = 1; o < 128; o <<= 1) {
        int v = (i >= o) ? lds[t - o] : 0;
        __syncthreads();
        lds[t] += v;
        __syncthreads();
    }
    int lb, ebase, bs;
    if (b < nbA) { lb = b;       ebase = 0;     bs = lb; }
    else         { lb = b - nbA; ebase = AOFFv; bs = 128 + lb; }
    int carry = (lb > 0) ? lds[bs - 1] : 0;
    int idx = ebase + lb * 1024 + t * 4;
#pragma unroll
    for (int j = 0; j < 4; ++j) {
        int v = inc[idx + j] + carry;
        inc[idx + j] = v;
        cursor[idx + j] = v - cnt[idx + j];
    }
}

__global__ __launch_bounds__(256) void csr_pos(
    const int* __restrict__ dA, int EA, const int* __restrict__ dB, int EB,
    int* __restrict__ cursor, int* __restrict__ posA, int* __restrict__ posB, int AOFFv)
{
    int i = blockIdx.x * 256 + threadIdx.x;
    if (i < EA)           posA[i] = atomicAdd(cursor + dA[i], 1);
    else if (i - EA < EB) posB[i - EA] = atomicAdd(cursor + AOFFv + dB[i - EA], 1);
}

// ================= async persistent edge MLP (r9/r11: __syncthreads) =================

__device__ __forceinline__ void ln_relu32(f32x4 acc[4],
    const float* __restrict__ b, const float* __restrict__ g, const float* __restrict__ be,
    float* s_red, float* s_ms, int rb, int cb, int n15, int q, int wcol, int t)
{
#pragma unroll
    for (int ct = 0; ct < 4; ++ct) {
        float bb = b[cb + ct * 16 + n15];
#pragma unroll
        for (int r = 0; r < 4; ++r) acc[ct][r] += bb;
    }
    float sum[4], ss[4];
#pragma unroll
    for (int r = 0; r < 4; ++r) {
        sum[r] = acc[0][r] + acc[1][r] + acc[2][r] + acc[3][r];
        ss[r]  = acc[0][r]*acc[0][r] + acc[1][r]*acc[1][r]
               + acc[2][r]*acc[2][r] + acc[3][r]*acc[3][r];
    }
#pragma unroll
    for (int off = 1; off < 16; off <<= 1) {
#pragma unroll
        for (int r = 0; r < 4; ++r) {
            sum[r] += __shfl_xor(sum[r], off, 64);
            ss[r]  += __shfl_xor(ss[r],  off, 64);
        }
    }
    if (n15 == 0) {
#pragma unroll
        for (int r = 0; r < 4; ++r) {
            int row = rb + q * 4 + r;
            s_red[row * 4 + wcol * 2 + 0] = sum[r];
            s_red[row * 4 + wcol * 2 + 1] = ss[r];
        }
    }
    __syncthreads();
    if (t < TE2) {
        float sm = s_red[t * 4 + 0] + s_red[t * 4 + 2];
        float sq = s_red[t * 4 + 1] + s_red[t * 4 + 3];
        float mean = sm * (1.f / 128.f);
        float var  = sq * (1.f / 128.f) - mean * mean;
        s_ms[t * 2 + 0] = mean;
        s_ms[t * 2 + 1] = rsqrtf(var + 1e-5f);
    }
    __syncthreads();
#pragma unroll
    for (int ct = 0; ct < 4; ++ct) {
        float gg = g[cb + ct * 16 + n15], bb = be[cb + ct * 16 + n15];
#pragma unroll
        for (int r = 0; r < 4; ++r) {
            int row = rb + q * 4 + r;
            float v = (acc[ct][r] - s_ms[row * 2 + 0]) * s_ms[row * 2 + 1] * gg + bb;
            acc[ct][r] = fmaxf(v, 0.f);
        }
    }
}

// x-buffer: [32 rows][512B]; 16B unit u of row r at (u ^ (r&7)). h = units 0..15,
// bond = 16..31. f1/f2: [32][256B], unit u at (u ^ (r&7)). Weights: [kb][512 units],
// unit l (= n*4+q) at l ^ ((n>>1)&3).
template<bool HBF16>
__global__ __launch_bounds__(256, 1) void edge_async(
    const void* __restrict__ hsrc, const float* __restrict__ bond,
    const int* __restrict__ src, const int* __restrict__ dstpos,
    const unsigned short* __restrict__ Wp1g, const unsigned short* __restrict__ Wp2g,
    const float* __restrict__ b1, const float* __restrict__ g1, const float* __restrict__ be1,
    const float* __restrict__ b2, const float* __restrict__ g2, const float* __restrict__ be2,
    unsigned short* __restrict__ ebh, int E, int ntiles, int chunk)
{
    __shared__ unsigned short s_w1[32768];       // 64KB
    __shared__ unsigned short s_w2[16384];       // 32KB
    __shared__ unsigned short s_x[2][8192];      // 2 x 16KB
    __shared__ int   s_meta[MAXT * 64];          // [tile][src 0..31 | dst 32..63]
    __shared__ float s_red[TE2 * 4];
    __shared__ float s_ms[TE2 * 2];

    int t = threadIdx.x;
    int tile0 = blockIdx.x * chunk;
    int myT = ntiles - tile0;
    if (myT > chunk) myT = chunk;

    // ---- prologue: weights + meta -> LDS ----
    {
        const uint4* w1 = (const uint4*)Wp1g;
        for (int u = t; u < 4096; u += 256) {
            int kb = u >> 9, l = u & 511, n = l >> 2;
            *(uint4*)((char*)s_w1 + kb * 8192 + ((l ^ ((n >> 1) & 3)) << 4)) = w1[u];
        }
        const uint4* w2 = (const uint4*)Wp2g;
        for (int u = t; u < 2048; u += 256) {
            int kb = u >> 9, l = u & 511, n = l >> 2;
            *(uint4*)((char*)s_w2 + kb * 8192 + ((l ^ ((n >> 1) & 3)) << 4)) = w2[u];
        }
        for (int x = t; x < myT * 64; x += 256) {
            int ti = x >> 6, r = x & 63;
            int ge = (tile0 + ti) * TE2 + (r & 31);
            int v;
            if (r < 32) v = (ge < E) ? src[ge] : 0;
            else        v = (ge < E) ? dstpos[ge] : -1;
            s_meta[x] = v;
        }
    }
    __syncthreads();
    if (myT <= 0) return;

    int r0  = t >> 5, k4 = t & 31;   // fp32 chunks: rows r0+8j
    int r0h = t >> 4, k8 = t & 15;   // 16B chunks: rows r0h+16j

    // ---- stage tile 0 into buf 0 ----
    {
        if (HBF16) {
            const unsigned short* hp = (const unsigned short*)hsrc;
#pragma unroll
            for (int j = 0; j < 2; ++j) {
                int row = r0h + 16 * j;
                int sv = s_meta[row];
                uint4 v = *(const uint4*)(hp + (size_t)sv * 128 + k8 * 8);
                *(uint4*)((char*)&s_x[0][0] + row * 512 + ((k8 ^ (row & 7)) << 4)) = v;
            }
        } else {
            const float* hp = (const float*)hsrc;
#pragma unroll
            for (int j = 0; j < 4; ++j) {
                int row = r0 + 8 * j;
                int sv = s_meta[row];
                float4 v = *(const float4*)(hp + (size_t)sv * 128 + k4 * 4);
                ushort4 o; o.x = f2h(v.x); o.y = f2h(v.y); o.z = f2h(v.z); o.w = f2h(v.w);
                *(ushort4*)((char*)&s_x[0][0] + row * 512
                            + (((k4 >> 1) ^ (row & 7)) << 4) + (k4 & 1) * 8) = o;
            }
        }
#pragma unroll
        for (int j = 0; j < 4; ++j) {
            int row = r0 + 8 * j;
            int ge = tile0 * TE2 + row;
            float4 v = make_float4(0, 0, 0, 0);
            if (ge < E) v = *(const float4*)(bond + (size_t)ge * 128 + k4 * 4);
            ushort4 o; o.x = f2h(v.x); o.y = f2h(v.y); o.z = f2h(v.z); o.w = f2h(v.w);
            *(ushort4*)((char*)&s_x[0][0] + row * 512
                        + (((16 + (k4 >> 1)) ^ (row & 7)) << 4) + (k4 & 1) * 8) = o;
        }
    }
    __syncthreads();

    int lane = t & 63, w = t >> 6;
    int n15 = lane & 15, q = lane >> 4;
    int rb = (w & 1) * 16, cb = (w >> 1) * 64, wcol = w >> 1;

    int c = 0;
    for (int i = 0; i < myT; ++i) {
        // ---- issue next-tile loads into registers (overlap with GEMMs) ----
        bool hasN = (i + 1 < myT);
        uint4  nh16[2]; float4 nh32[4]; float4 nb[4];
        if (hasN) {
            int mt = i + 1, tb = (tile0 + mt) * TE2;
            if (HBF16) {
                const unsigned short* hp = (const unsigned short*)hsrc;
#pragma unroll
                for (int j = 0; j < 2; ++j) {
                    int row = r0h + 16 * j;
                    int sv = s_meta[mt * 64 + row];
                    nh16[j] = *(const uint4*)(hp + (size_t)sv * 128 + k8 * 8);
                }
            } else {
                const float* hp = (const float*)hsrc;
#pragma unroll
                for (int j = 0; j < 4; ++j) {
                    int row = r0 + 8 * j;
                    int sv = s_meta[mt * 64 + row];
                    nh32[j] = *(const float4*)(hp + (size_t)sv * 128 + k4 * 4);
                }
            }
#pragma unroll
            for (int j = 0; j < 4; ++j) {
                int row = r0 + 8 * j, ge = tb + row;
                nb[j] = make_float4(0, 0, 0, 0);
                if (ge < E) nb[j] = *(const float4*)(bond + (size_t)ge * 128 + k4 * 4);
            }
        }

        const unsigned short* xb = &s_x[c][0];
        unsigned short* f1b = (unsigned short*)&s_x[c ^ 1][0];   // alias idle buffer
        unsigned short* f2b = f1b + 4096;

        // ---- GEMM1: [h | bond] x Wp1 (LDS weights) ----
        f32x4 acc[4];
        f32x4 zero = {0.f, 0.f, 0.f, 0.f};
#pragma unroll
        for (int ct = 0; ct < 4; ++ct) acc[ct] = zero;
#pragma unroll
        for (int kb = 0; kb < 8; ++kb) {
            f16x8 af = *(const f16x8*)((const char*)xb + (rb + n15) * 512
                                       + (((kb * 4 + q) ^ (n15 & 7)) << 4));
#pragma unroll
            for (int ct = 0; ct < 4; ++ct) {
                int n = cb + ct * 16 + n15, l = n * 4 + q;
                f16x8 bf = *(const f16x8*)((const char*)s_w1 + kb * 8192
                                           + ((l ^ ((n >> 1) & 3)) << 4));
                acc[ct] = __builtin_amdgcn_mfma_f32_16x16x32_f16(af, bf, acc[ct], 0, 0, 0);
            }
        }
        ln_relu32(acc, b1, g1, be1, s_red, s_ms, rb, cb, n15, q, wcol, t);
#pragma unroll
        for (int ct = 0; ct < 4; ++ct)
#pragma unroll
            for (int r = 0; r < 4; ++r) {
                int row = rb + q * 4 + r, col = cb + ct * 16 + n15;
                *(unsigned short*)((char*)f1b + row * 256
                                   + ((col * 2) ^ ((row & 7) << 4))) = f2h(acc[ct][r]);
            }
        __syncthreads();

        // ---- GEMM2: f1 x Wp2 ----
#pragma unroll
        for (int ct = 0; ct < 4; ++ct) acc[ct] = zero;
#pragma unroll
        for (int kb = 0; kb < 4; ++kb) {
            f16x8 af = *(const f16x8*)((const char*)f1b + (rb + n15) * 256
                                       + (((kb * 4 + q) ^ (n15 & 7)) << 4));
#pragma unroll
            for (int ct = 0; ct < 4; ++ct) {
                int n = cb + ct * 16 + n15, l = n * 4 + q;
                f16x8 bf = *(const f16x8*)((const char*)s_w2 + kb * 8192
                                           + ((l ^ ((n >> 1) & 3)) << 4));
                acc[ct] = __builtin_amdgcn_mfma_f32_16x16x32_f16(af, bf, acc[ct], 0, 0, 0);
            }
        }
        ln_relu32(acc, b2, g2, be2, s_red, s_ms, rb, cb, n15, q, wcol, t);
#pragma unroll
        for (int ct = 0; ct < 4; ++ct)
#pragma unroll
            for (int r = 0; r < 4; ++r) {
                int row = rb + q * 4 + r, col = cb + ct * 16 + n15;
                *(unsigned short*)((char*)f2b + row * 256
                                   + ((col * 2) ^ ((row & 7) << 4))) = f2h(acc[ct][r]);
            }
        __syncthreads();

        // ---- coalesced row stores to dst-sorted slots ----
#pragma unroll
        for (int j = 0; j < 2; ++j) {
            int row = r0h + 16 * j;
            int p = s_meta[i * 64 + 32 + row];
            if (p >= 0) {
                uint4 v = *(const uint4*)((const char*)f2b + row * 256
                                          + ((k8 ^ (row & 7)) << 4));
                *(uint4*)(ebh + (size_t)p * 128 + k8 * 8) = v;
            }
        }
        __syncthreads();   // all f1/f2/x reads done -> safe to overwrite alias buffer

        // ---- write prefetched tile i+1 into the idle buffer ----
        if (hasN) {
            unsigned short* dstb = (unsigned short*)&s_x[c ^ 1][0];
            if (HBF16) {
#pragma unroll
                for (int j = 0; j < 2; ++j) {
                    int row = r0h + 16 * j;
                    *(uint4*)((char*)dstb + row * 512 + ((k8 ^ (row & 7)) << 4)) = nh16[j];
                }
            } else {
#pragma unroll
                for (int j = 0; j < 4; ++j) {
                    int row = r0 + 8 * j;
                    ushort4 o;
                    o.x = f2h(nh32[j].x); o.y = f2h(nh32[j].y);
                    o.z = f2h(nh32[j].z); o.w = f2h(nh32[j].w);
                    *(ushort4*)((char*)dstb + row * 512
                                + (((k4 >> 1) ^ (row & 7)) << 4) + (k4 & 1) * 8) = o;
                }
            }
#pragma unroll
            for (int j = 0; j < 4; ++j) {
                int row = r0 + 8 * j;
                ushort4 o;
                o.x = f2h(nb[j].x); o.y = f2h(nb[j].y); o.z = f2h(nb[j].z); o.w = f2h(nb[j].w);
                *(ushort4*)((char*)dstb + row * 512
                            + (((16 + (k4 >> 1)) ^ (row & 7)) << 4) + (k4 & 1) * 8) = o;
            }
        }
        __syncthreads();
        c ^= 1;
    }
}

// ================= MLP kernels (r8 / fallback) =================

template<int KB>
__device__ __forceinline__ void gemm_f16(const unsigned short* s_in, int stride,
    const unsigned short* __restrict__ Wp, int rb, int cb, int n15, int q, f32x4 acc[2][4])
{
    f32x4 zero = {0.f, 0.f, 0.f, 0.f};
#pragma unroll
    for (int m = 0; m < 2; ++m)
#pragma unroll
        for (int ct = 0; ct < 4; ++ct) acc[m][ct] = zero;
#pragma unroll
    for (int kb = 0; kb < KB; ++kb) {
        f16x8 af0 = *(const f16x8*)(s_in + (rb + n15) * stride + kb * 32 + q * 8);
        f16x8 af1 = *(const f16x8*)(s_in + (rb + 16 + n15) * stride + kb * 32 + q * 8);
        const unsigned short* wb = Wp + (size_t)kb * 4096 + q * 8;
#pragma unroll
        for (int ct = 0; ct < 4; ++ct) {
            f16x8 bf = *(const f16x8*)(wb + (cb + ct * 16 + n15) * 32);
            acc[0][ct] = __builtin_amdgcn_mfma_f32_16x16x32_f16(af0, bf, acc[0][ct], 0, 0, 0);
            acc[1][ct] = __builtin_amdgcn_mfma_f32_16x16x32_f16(af1, bf, acc[1][ct], 0, 0, 0);
        }
    }
}

__device__ __forceinline__ void ln_relu(f32x4 acc[2][4],
    const float* __restrict__ b, const float* __restrict__ g, const float* __restrict__ be,
    float* s_red, float* s_ms, int rb, int cb, int n15, int q, int wcol, int t)
{
#pragma unroll
    for (int ct = 0; ct < 4; ++ct) {
        float bb = b[cb + ct * 16 + n15];
#pragma unroll
        for (int m = 0; m < 2; ++m)
#pragma unroll
            for (int r = 0; r < 4; ++r) acc[m][ct][r] += bb;
    }
    float sum[2][4], ss[2][4];
#pragma unroll
    for (int m = 0; m < 2; ++m)
#pragma unroll
        for (int r = 0; r < 4; ++r) {
            sum[m][r] = acc[m][0][r] + acc[m][1][r] + acc[m][2][r] + acc[m][3][r];
            ss[m][r]  = acc[m][0][r]*acc[m][0][r] + acc[m][1][r]*acc[m][1][r]
                      + acc[m][2][r]*acc[m][2][r] + acc[m][3][r]*acc[m][3][r];
        }
#pragma unroll
    for (int off = 1; off < 16; off <<= 1) {
#pragma unroll
        for (int m = 0; m < 2; ++m)
#pragma unroll
            for (int r = 0; r < 4; ++r) {
                sum[m][r] += __shfl_xor(sum[m][r], off, 64);
                ss[m][r]  += __shfl_xor(ss[m][r],  off, 64);
            }
    }
    if (n15 == 0) {
#pragma unroll
        for (int m = 0; m < 2; ++m)
#pragma unroll
            for (int r = 0; r < 4; ++r) {
                int row = rb + m * 16 + q * 4 + r;
                s_red[row * 4 + wcol * 2 + 0] = sum[m][r];
                s_red[row * 4 + wcol * 2 + 1] = ss[m][r];
            }
    }
    __syncthreads();
    if (t < TE) {
        float sm = s_red[t * 4 + 0] + s_red[t * 4 + 2];
        float sq = s_red[t * 4 + 1] + s_red[t * 4 + 3];
        float mean = sm * (1.f / 128.f);
        float var  = sq * (1.f / 128.f) - mean * mean;
        s_ms[t * 2 + 0] = mean;
        s_ms[t * 2 + 1] = rsqrtf(var + 1e-5f);
    }
    __syncthreads();
#pragma unroll
    for (int ct = 0; ct < 4; ++ct) {
        float gg = g[cb + ct * 16 + n15], bb = be[cb + ct * 16 + n15];
#pragma unroll
        for (int m = 0; m < 2; ++m)
#pragma unroll
            for (int r = 0; r < 4; ++r) {
                int row = rb + m * 16 + q * 4 + r;
                float v = (acc[m][ct][r] - s_ms[row * 2 + 0]) * s_ms[row * 2 + 1] * gg + bb;
                acc[m][ct][r] = fmaxf(v, 0.f);
            }
    }
}

template<bool HBF16, bool CSR>
__global__ __launch_bounds__(256, 4) void edge_mlp(
    const void* __restrict__ hsrc, const float* __restrict__ bond,
    const int* __restrict__ src, const int* __restrict__ dstpos,
    const unsigned short* __restrict__ Wp1, const unsigned short* __restrict__ Wp2,
    const float* __restrict__ b1, const float* __restrict__ g1, const float* __restrict__ be1,
    const float* __restrict__ b2, const float* __restrict__ g2, const float* __restrict__ be2,
    float* __restrict__ agg, unsigned short* __restrict__ ebh, int E)
{
    __shared__ unsigned short s_x[TE * XS];
    __shared__ float s_red[TE * 4];
    __shared__ float s_ms[TE * 2];
    __shared__ int s_src[TE], s_idx[TE];
    unsigned short* s_y = s_x + 128;

    int t = threadIdx.x, eb = blockIdx.x * TE;
    if (t < TE) {
        int ge = eb + t;
        s_src[t] = (ge < E) ? src[ge] : -1;
        s_idx[t] = (ge < E) ? dstpos[ge] : -1;
    }
    __syncthreads();

    if (HBF16) {
        const unsigned short* hp = (const unsigned short*)hsrc;
        for (int c = t; c < TE * 16; c += 256) {
            int row = c >> 4, k8 = c & 15;
            int s = s_src[row];
            uint4 v = make_uint4(0, 0, 0, 0);
            if (s >= 0) v = *(const uint4*)(hp + (size_t)s * 128 + k8 * 8);
            *(uint4*)(s_x + row * XS + k8 * 8) = v;
        }
    } else {
        const float* hp = (const float*)hsrc;
        for (int c = t; c < TE * 32; c += 256) {
            int row = c >> 5, k4 = c & 31;
            int s = s_src[row];
            float4 v = make_float4(0, 0, 0, 0);
            if (s >= 0) v = *(const float4*)(hp + (size_t)s * 128 + k4 * 4);
            ushort4 o; o.x = f2h(v.x); o.y = f2h(v.y); o.z = f2h(v.z); o.w = f2h(v.w);
            *(ushort4*)(s_x + row * XS + k4 * 4) = o;
        }
    }
    for (int c = t; c < TE * 32; c += 256) {
        int row = c >> 5, k4 = c & 31;
        int ge = eb + row;
        float4 v = make_float4(0, 0, 0, 0);
        if (ge < E) v = *(const float4*)(bond + (size_t)ge * 128 + k4 * 4);
        ushort4 o; o.x = f2h(v.x); o.y = f2h(v.y); o.z = f2h(v.z); o.w = f2h(v.w);
        *(ushort4*)(s_x + row * XS + 128 + k4 * 4) = o;
    }
    __syncthreads();

    int l = t & 63, w = t >> 6;
    int n15 = l & 15, q = l >> 4;
    int rb = (w & 1) * 32, cb = (w >> 1) * 64, wcol = w >> 1;

    f32x4 acc[2][4];
    gemm_f16<8>(s_x, XS, Wp1, rb, cb, n15, q, acc);
    ln_relu(acc, b1, g1, be1, s_red, s_ms, rb, cb, n15, q, wcol, t);
#pragma unroll
    for (int m = 0; m < 2; ++m)
#pragma unroll
        for (int ct = 0; ct < 4; ++ct)
#pragma unroll
            for (int r = 0; r < 4; ++r)
                s_y[(rb + m * 16 + q * 4 + r) * XS + cb + ct * 16 + n15] = f2h(acc[m][ct][r]);
    __syncthreads();
    gemm_f16<4>(s_y, XS, Wp2, rb, cb, n15, q, acc);
    ln_relu(acc, b2, g2, be2, s_red, s_ms, rb, cb, n15, q, wcol, t);

    if (CSR) {
#pragma unroll
        for (int m = 0; m < 2; ++m)
#pragma unroll
            for (int ct = 0; ct < 4; ++ct)
#pragma unroll
                for (int r = 0; r < 4; ++r)
                    s_x[(rb + m * 16 + q * 4 + r) * XS + cb + ct * 16 + n15] = f2h(acc[m][ct][r]);
        __syncthreads();
        for (int c = t; c < TE * 16; c += 256) {
            int row = c >> 4, k8 = c & 15;
            int p = s_idx[row];
            if (p >= 0)
                *(uint4*)(ebh + (size_t)p * 128 + k8 * 8) =
                    *(const uint4*)(s_x + row * XS + k8 * 8);
        }
    } else {
#pragma unroll
        for (int m = 0; m < 2; ++m)
#pragma unroll
            for (int ct = 0; ct < 4; ++ct)
#pragma unroll
                for (int r = 0; r < 4; ++r) {
                    int row = rb + m * 16 + q * 4 + r;
                    int gd = s_idx[row];
                    if (gd >= 0)
                        atomicAdd(agg + (size_t)gd * D + cb + ct * 16 + n15, acc[m][ct][r]);
                }
    }
}

template<bool OUT_F16, bool CSR>
__global__ __launch_bounds__(256, 4) void node_mlp(
    const float* __restrict__ ax, const float* __restrict__ agg,
    const int* __restrict__ inc, const unsigned short* __restrict__ ebh,
    const unsigned short* __restrict__ Wp1, const unsigned short* __restrict__ Wp2,
    const unsigned short* __restrict__ Wp3,
    const float* __restrict__ b1, const float* __restrict__ g1, const float* __restrict__ be1,
    const float* __restrict__ b2, const float* __restrict__ g2, const float* __restrict__ be2,
    const float* __restrict__ b3, const float* __restrict__ g3, const float* __restrict__ be3,
    void* __restrict__ out, int N)
{
    __shared__ unsigned short s_x[TE * XS];
    __shared__ float s_red[TE * 4];
    __shared__ float s_ms[TE * 2];
    __shared__ int s_beg[TE], s_end[TE];
    unsigned short* s_y = s_x + 128;

    int t = threadIdx.x, nb = blockIdx.x * TE;

    if (CSR && t < TE) {
        int gr = nb + t, b0 = 0, e0 = 0;
        if (gr < N) { e0 = inc[gr]; b0 = (gr == 0) ? 0 : inc[gr - 1]; }
        s_beg[t] = b0; s_end[t] = e0;
    }

    for (int c = t; c < TE * 32; c += 256) {
        int row = c >> 5, k4 = c & 31;
        int gr = nb + row;
        float4 v = make_float4(0, 0, 0, 0);
        if (gr < N) v = *(const float4*)(ax + (size_t)gr * 128 + k4 * 4);
        ushort4 o; o.x = f2h(v.x); o.y = f2h(v.y); o.z = f2h(v.z); o.w = f2h(v.w);
        *(ushort4*)(s_x + row * XS + k4 * 4) = o;
    }

    if (CSR) {
        __syncthreads();
        int r = t >> 2, s4 = t & 3;
        float a[32];
#pragma unroll
        for (int k = 0; k < 32; ++k) a[k] = 0.f;
        int jb = s_beg[r], je = s_end[r];
        int j = jb;
        for (; j + 2 <= je; j += 2) {
            const unsigned short* rp0 = ebh + (size_t)j * 128 + s4 * 32;
            const unsigned short* rp1 = rp0 + 128;
            f16x8 a0 = *(const f16x8*)rp0;
            f16x8 a1 = *(const f16x8*)(rp0 + 8);
            f16x8 a2 = *(const f16x8*)(rp0 + 16);
            f16x8 a3 = *(const f16x8*)(rp0 + 24);
            f16x8 b0 = *(const f16x8*)rp1;
            f16x8 b1v = *(const f16x8*)(rp1 + 8);
            f16x8 b2v = *(const f16x8*)(rp1 + 16);
            f16x8 b3v = *(const f16x8*)(rp1 + 24);
#pragma unroll
            for (int k = 0; k < 8; ++k) {
                a[k]      += (float)a0[k];
                a[8 + k]  += (float)a1[k];
                a[16 + k] += (float)a2[k];
                a[24 + k] += (float)a3[k];
            }
#pragma unroll
            for (int k = 0; k < 8; ++k) {
                a[k]      += (float)b0[k];
                a[8 + k]  += (float)b1v[k];
                a[16 + k] += (float)b2v[k];
                a[24 + k] += (float)b3v[k];
            }
        }
        if (j < je) {
            const unsigned short* rp = ebh + (size_t)j * 128 + s4 * 32;
            f16x8 v0 = *(const f16x8*)rp;
            f16x8 v1 = *(const f16x8*)(rp + 8);
            f16x8 v2 = *(const f16x8*)(rp + 16);
            f16x8 v3 = *(const f16x8*)(rp + 24);
#pragma unroll
            for (int k = 0; k < 8; ++k) {
                a[k]      += (float)v0[k];
                a[8 + k]  += (float)v1[k];
                a[16 + k] += (float)v2[k];
                a[24 + k] += (float)v3[k];
            }
        }
        unsigned short* op = s_x + r * XS + 128 + s4 * 32;
#pragma unroll
        for (int blk = 0; blk < 4; ++blk) {
            f16x8 h;
#pragma unroll
            for (int k = 0; k < 8; ++k) h[k] = (_Float16)a[blk * 8 + k];
            *(f16x8*)(op + blk * 8) = h;
        }
    } else {
        for (int c = t; c < TE * 32; c += 256) {
            int row = c >> 5, k4 = c & 31;
            int gr = nb + row;
            float4 v = make_float4(0, 0, 0, 0);
            if (gr < N) v = *(const float4*)(agg + (size_t)gr * 128 + k4 * 4);
            ushort4 o; o.x = f2h(v.x); o.y = f2h(v.y); o.z = f2h(v.z); o.w = f2h(v.w);
            *(ushort4*)(s_x + row * XS + 128 + k4 * 4) = o;
        }
    }
    __syncthreads();

    int l = t & 63, w = t >> 6;
    int n15 = l & 15, q = l >> 4;
    int rb = (w & 1) * 32, cb = (w >> 1) * 64, wcol = w >> 1;

    f32x4 acc[2][4];
    gemm_f16<8>(s_x, XS, Wp1, rb, cb, n15, q, acc);
    ln_relu(acc, b1, g1, be1, s_red, s_ms, rb, cb, n15, q, wcol, t);
#pragma unroll
    for (int m = 0; m < 2; ++m)
#pragma unroll
        for (int ct = 0; ct < 4; ++ct)
#pragma unroll
            for (int r = 0; r < 4; ++r)
                s_y[(rb + m * 16 + q * 4 + r) * XS + cb + ct * 16 + n15] = f2h(acc[m][ct][r]);
    __syncthreads();
    gemm_f16<4>(s_y, XS, Wp2, rb, cb, n15, q, acc);
    ln_relu(acc, b2, g2, be2, s_red, s_ms, rb, cb, n15, q, wcol, t);
#pragma unroll
    for (int m = 0; m < 2; ++m)
#pragma unroll
        for (int ct = 0; ct < 4; ++ct)
#pragma unroll
            for (int r = 0; r < 4; ++r)
                s_x[(rb + m * 16 + q * 4 + r) * XS + 128 + cb + ct * 16 + n15] = f2h(acc[m][ct][r]);
    __syncthreads();
    gemm_f16<8>(s_x, XS, Wp3, rb, cb, n15, q, acc);
    ln_relu(acc, b3, g3, be3, s_red, s_ms, rb, cb, n15, q, wcol, t);

#pragma unroll
    for (int m = 0; m < 2; ++m)
#pragma unroll
        for (int ct = 0; ct < 4; ++ct)
#pragma unroll
            for (int r = 0; r < 4; ++r) {
                int row = rb + m * 16 + q * 4 + r;
                int gr = nb + row;
                int col = cb + ct * 16 + n15;
                if (gr < N) {
                    if (OUT_F16)
                        ((unsigned short*)out)[(size_t)gr * D + col] = f2h(acc[m][ct][r]);
                    else
                        ((float*)out)[(size_t)gr * D + col] = acc[m][ct][r];
                }
            }
}

extern "C" void kernel_launch(void* const* d_in, const int* in_sizes, int n_in,
                              void* d_out, int out_size, void* d_ws, size_t ws_size,
                              hipStream_t stream)
{
    const float* h2   = (const float*)d_in[0];
    const float* ax1  = (const float*)d_in[1];
    const float* ax0  = (const float*)d_in[2];
    const float* bx2  = (const float*)d_in[3];
    const float* bx1  = (const float*)d_in[4];
    const float* brW1 = (const float*)d_in[5];
    const float* brb1 = (const float*)d_in[6];
    const float* brg1 = (const float*)d_in[7];
    const float* brbe1= (const float*)d_in[8];
    const float* brW2 = (const float*)d_in[9];
    const float* brb2 = (const float*)d_in[10];
    const float* brg2 = (const float*)d_in[11];
    const float* brbe2= (const float*)d_in[12];
    const float* sW1  = (const float*)d_in[13];
    const float* sb1  = (const float*)d_in[14];
    const float* sg1  = (const float*)d_in[15];
    const float* sbe1 = (const float*)d_in[16];
    const float* sW2  = (const float*)d_in[17];
    const float* sb2  = (const float*)d_in[18];
    const float* sg2  = (const float*)d_in[19];
    const float* sbe2 = (const float*)d_in[20];
    const float* hW   = (const float*)d_in[21];
    const float* hb   = (const float*)d_in[22];
    const float* hg   = (const float*)d_in[23];
    const float* hbe  = (const float*)d_in[24];
    const int*   src2 = (const int*)d_in[25];
    const int*   dst2 = (const int*)d_in[26];
    const int*   src1 = (const int*)d_in[27];
    const int*   dst1 = (const int*)d_in[28];

    int n2 = in_sizes[0] / D;
    int n1 = in_sizes[1] / D;
    int n0 = in_sizes[2] / D;

    unsigned short* Wp = (unsigned short*)d_ws;   // 262144 fp16 = 512 KB

    const unsigned short* pBr1[2] = { Wp + 0,      Wp + 32768 };
    const unsigned short* pBr2[2] = { Wp + 65536,  Wp + 65536  + 16384 };
    const unsigned short* pS1 [2] = { Wp + 98304,  Wp + 98304  + 32768 };
    const unsigned short* pS2 [2] = { Wp + 163840, Wp + 163840 + 16384 };
    const unsigned short* pH  [2] = { Wp + 196608, Wp + 196608 + 32768 };

    // ---- workspace layout ----
    int nbA = (n1 + 1023) / 1024, nbB = (n0 + 1023) / 1024;
    int AOFFv = nbA * 1024;
    int AN = AOFFv + nbB * 1024;
    auto al = [](size_t x) { return (x + 255) & ~(size_t)255; };
    size_t o = 524288;
    size_t cnt_o  = o; o = al(o + (size_t)AN * 4);
    size_t inc_o  = o; o = al(o + (size_t)AN * 4);
    size_t cur_o  = o; o = al(o + (size_t)AN * 4);
    size_t bsum_o = o; o = al(o + 1024);
    size_t posA_o = o; o = al(o + (size_t)n2 * 4);
    size_t posB_o = o; o = al(o + (size_t)n1 * 4);
    size_t h1_o   = o; o = al(o + (size_t)n1 * 256);
    size_t ebh_o  = o; o = al(o + (size_t)n2 * 256);
    size_t o_csr  = o;
    bool use_csr = (nbA <= 128) && (nbB <= 128) && (ws_size >= o_csr);

    int t2e = (n2 + TE - 1) / TE, t1e = (n1 + TE - 1) / TE;
    int t1n = (n1 + TE - 1) / TE, t0n = (n0 + TE - 1) / TE;

    if (use_csr) {
        int*            cnt    = (int*)((char*)d_ws + cnt_o);
        int*            inc    = (int*)((char*)d_ws + inc_o);
        int*            cursor = (int*)((char*)d_ws + cur_o);
        int*            bsum   = (int*)((char*)d_ws + bsum_o);
        int*            posA   = (int*)((char*)d_ws + posA_o);
        int*            posB   = (int*)((char*)d_ws + posB_o);
        unsigned short* h1     = (unsigned short*)((char*)d_ws + h1_o);
        unsigned short* ebh    = (unsigned short*)((char*)d_ws + ebh_o);

        // ---- setup: 5 dispatches ----
        int EG = (n2 + n1 + 255) / 256;
        pack_zero<<<dim3(1024), dim3(256), 0, stream>>>(brW1, brW2, sW1, sW2, hW, Wp, cnt, AN);
        csr_hist  <<<dim3(EG),        dim3(256), 0, stream>>>(dst2, n2, dst1, n1, cnt, AOFFv);
        csr_scanA <<<dim3(nbA + nbB), dim3(256), 0, stream>>>(cnt, inc, bsum, nbA, AOFFv);
        csr_scanC2<<<dim3(nbA + nbB), dim3(256), 0, stream>>>(cnt, inc, bsum, cursor, nbA, nbB, AOFFv);
        csr_pos   <<<dim3(EG),        dim3(256), 0, stream>>>(dst2, n2, dst1, n1, cursor, posA, posB, AOFFv);

        // async-edge tiling (level 2 only; level-1 async regressed in r9)
        int tiles2 = (n2 + TE2 - 1) / TE2, chunk2 = (tiles2 + 255) / 256;
        bool asy2 = (chunk2 <= MAXT);

        // ---- iteration 0 (level 2 -> 1) ----
        if (asy2)
            edge_async<false><<<dim3(256), dim3(256), 0, stream>>>(
                h2, bx2, src2, posA, pBr1[0], pBr2[0],
                brb1, brg1, brbe1, brb2, brg2, brbe2, ebh, n2, tiles2, chunk2);
        else
            edge_mlp<false, true><<<dim3(t2e), dim3(256), 0, stream>>>(
                h2, bx2, src2, posA, pBr1[0], pBr2[0],
                brb1, brg1, brbe1, brb2, brg2, brbe2, nullptr, ebh, n2);
        node_mlp<true, true><<<dim3(t1n), dim3(256), 0, stream>>>(
            ax1, nullptr, inc, ebh, pS1[0], pS2[0], pH[0],
            sb1, sg1, sbe1, sb2, sg2, sbe2, hb, hg, hbe, h1, n1);

        // ---- iteration 1 (level 1 -> 0) ----
        edge_mlp<true, true><<<dim3(t1e), dim3(256), 0, stream>>>(
            h1, bx1, src1, posB, pBr1[1], pBr2[1],
            brb1 + D, brg1 + D, brbe1 + D, brb2 + D, brg2 + D, brbe2 + D, nullptr, ebh, n1);
        node_mlp<false, true><<<dim3(t0n), dim3(256), 0, stream>>>(
            ax0, nullptr, inc + AOFFv, ebh, pS1[1], pS2[1], pH[1],
            sb1 + D, sg1 + D, sbe1 + D, sb2 + D, sg2 + D, sbe2 + D,
            hb + D, hg + D, hbe + D, d_out, n0);
    } else {
        // fallback: atomic-aggregation path
        float*          agg = (float*)((char*)d_ws + 524288);
        unsigned short* h1  = (unsigned short*)(agg + (size_t)n1 * D);

        pack_zero<<<dim3(1024), dim3(256), 0, stream>>>(brW1, brW2, sW1, sW2, hW, Wp, nullptr, 0);

        hipMemsetAsync(agg, 0, (size_t)n1 * D * sizeof(float), stream);
        edge_mlp<false, false><<<dim3(t2e), dim3(256), 0, stream>>>(
            h2, bx2, src2, dst2, pBr1[0], pBr2[0],
            brb1, brg1, brbe1, brb2, brg2, brbe2, agg, nullptr, n2);
        node_mlp<true, false><<<dim3(t1n), dim3(256), 0, stream>>>(
            ax1, agg, nullptr, nullptr, pS1[0], pS2[0], pH[0],
            sb1, sg1, sbe1, sb2, sg2, sbe2, hb, hg, hbe, h1, n1);

        hipMemsetAsync(agg, 0, (size_t)n0 * D * sizeof(float), stream);
        edge_mlp<true, false><<<dim3(t1e), dim3(256), 0, stream>>>(
            h1, bx1, src1, dst1, pBr1[1], pBr2[1],
            brb1 + D, brg1 + D, brbe1 + D, brb2 + D, brg2 + D, brbe2 + D, agg, nullptr, n1);
        node_mlp<false, false><<<dim3(t0n), dim3(256), 0, stream>>>(
            ax0, agg, nullptr, nullptr, pS1[1], pS2[1], pH[1],
            sb1 + D, sg1 + D, sbe1 + D, sb2 + D, sg2 + D, sbe2 + D,
            hb + D, hg + D, hbe + D, d_out, n0);
    }
}